// Round 6
// baseline (325.850 us; speedup 1.0000x reference)
//
#include <hip/hip_runtime.h>
#include <hip/hip_bf16.h>
#include <cstdint>

#define NNODES 20000
#define NEDGES 640000
#define ETOT   (NEDGES + NNODES)
#define NGROUP 64
#define HC     256
#define DOUT   32
#define EBLK   5120                     // edges per CSR-build block (divides NEDGES)
#define NBLK   (NEDGES / EBLK)          // 125
#define CBLK   ((NNODES + 255) / 256)   // 79 node blocks

typedef short bf16x8 __attribute__((ext_vector_type(8)));  // 8 bf16 in 4 VGPRs
typedef short s16x4  __attribute__((ext_vector_type(4)));
typedef float f32x4  __attribute__((ext_vector_type(4)));
typedef float f32x2  __attribute__((ext_vector_type(2)));
typedef int   s32x4  __attribute__((ext_vector_type(4)));
typedef unsigned int u32x4 __attribute__((ext_vector_type(4)));

__device__ __forceinline__ float b2f(__hip_bfloat16 v) { return __bfloat162float(v); }
__device__ __forceinline__ float bs2f(short v) {
    union { unsigned int u; float f; } c; c.u = ((unsigned int)(unsigned short)v) << 16; return c.f;
}
__device__ __forceinline__ short f2bs(float v) {
    __hip_bfloat16 b = __float2bfloat16(v);
    union { __hip_bfloat16 b; short s; } u; u.b = b; return u.s;
}
// float load robust to fp32 vs bf16 storage
__device__ __forceinline__ float ldf(const void* __restrict__ p, size_t i, int bf) {
    return bf ? __bfloat162float(((const __hip_bfloat16*)p)[i]) : ((const float*)p)[i];
}
// int load robust to int32 vs int64 storage (little-endian low word)
__device__ __forceinline__ int ld_idx(const int* __restrict__ p, size_t i, int f64) {
    return f64 ? p[2 * i] : p[i];
}
// monotone float<->uint map for atomicMax on floats (any sign)
__device__ __forceinline__ unsigned enc_f(float f) {
    unsigned u = __float_as_uint(f);
    return (u >> 31) ? ~u : (u | 0x80000000u);
}
__device__ __forceinline__ float dec_f(unsigned e) {
    return (e >> 31) ? __uint_as_float(e & 0x7FFFFFFFu) : __uint_as_float(~e);
}

// ---------------- probe (ballot-parallel) + readout/gmax init ----------------
// flag[0]: edge_index int64?  flag[1]: floats bf16?
__global__ void k_probe(const unsigned int* __restrict__ xw, const int* __restrict__ ei,
                        int* __restrict__ flag, float* __restrict__ sx, int* __restrict__ cnt,
                        unsigned int* __restrict__ gmaxu) {
    int t = threadIdx.x;
    for (int i = t; i < NGROUP * HC; i += 256) sx[i] = 0.f;
    if (t < NGROUP) cnt[t] = 0;
    if (t < 64) gmaxu[t] = 0x007FFFFFu;  // enc(-inf)
    if (t < 64) {
        int l = t;
        int ones = 0, zeros = 0;
#pragma unroll
        for (int r = 0; r < 4; r++) {
            unsigned long long b1 = __ballot((xw[r * 64 + l] >> 14) & 1);
            unsigned long long b2 = __ballot(ei[2 * (r * 64 + l) + 1] == 0);
            ones  += __popcll(b1);
            zeros += __popcll(b2);
        }
        if (l == 0) { flag[1] = (ones < 64) ? 1 : 0; flag[0] = (zeros > 200) ? 1 : 0; }
    }
}

// ---------------- CSR build, atomic-free (per-block LDS histograms) ----------------
// Self-loops are NOT histogrammed: deg = colsum + 1 and csr[off[n]] = n is written
// directly by k_base. Each block handles exactly EBLK real edges -> no guards,
// 16B-aligned dwordx4 edge loads.
__global__ __launch_bounds__(256) void k_lhist(const int* __restrict__ ei,
                                               int* __restrict__ H,
                                               const int* __restrict__ flag) {
    __shared__ int hl[NNODES];  // 80 KB
    int t = threadIdx.x, b = blockIdx.x, f = flag[0];
    s32x4* hl4 = reinterpret_cast<s32x4*>(hl);
    for (int i = t; i < NNODES / 4; i += 256) hl4[i] = (s32x4){0, 0, 0, 0};
    __syncthreads();
    int s0 = b * EBLK;
    if (f) {
        const int* d64 = ei + 2 * NEDGES;   // low words at d64[2*i]
        for (int i0 = s0; i0 < s0 + EBLK; i0 += 512) {
            int i = i0 + 2 * t;
            s32x4 v = *reinterpret_cast<const s32x4*>(d64 + 2 * (size_t)i);
            atomicAdd(&hl[v[0]], 1);
            atomicAdd(&hl[v[2]], 1);
        }
    } else {
        const int* d32 = ei + NEDGES;
        for (int i0 = s0; i0 < s0 + EBLK; i0 += 1024) {
            int i = i0 + 4 * t;
            s32x4 v = *reinterpret_cast<const s32x4*>(d32 + i);
            atomicAdd(&hl[v[0]], 1); atomicAdd(&hl[v[1]], 1);
            atomicAdd(&hl[v[2]], 1); atomicAdd(&hl[v[3]], 1);
        }
    }
    __syncthreads();
    s32x4* Hb4 = reinterpret_cast<s32x4*>(H + (size_t)b * NNODES);
    for (int i = t; i < NNODES / 4; i += 256) Hb4[i] = hl4[i];
}

// deg[n] = 1 (self-loop) + sum_b H[b][n]; per-block totals for k_base's tiny scan.
__global__ __launch_bounds__(256) void k_colsum(const int* __restrict__ H,
                                                int* __restrict__ deg,
                                                int* __restrict__ bsum) {
    __shared__ int wred[4];
    int t = threadIdx.x, n = blockIdx.x * 256 + t;
    int s = 0;
    if (n < NNODES) {
#pragma unroll 5
        for (int b = 0; b < NBLK; b++) s += H[(size_t)b * NNODES + n];
        s += 1;  // self-loop
        deg[n] = s;
    }
    int r = s;
#pragma unroll
    for (int o = 1; o < 64; o <<= 1) r += __shfl_xor(r, o);
    if ((t & 63) == 0) wred[t >> 6] = r;
    __syncthreads();
    if (t == 0) bsum[blockIdx.x] = wred[0] + wred[1] + wred[2] + wred[3];
}

// Per 256-node block: block offset = scan of bsum (done in-kernel by wave 0),
// intra-block shuffle scan of deg -> off[n], self-loop csr entry at off[n], then
// per-block H bases (prefix over NBLK, +1 for the reserved self-loop slot).
__global__ __launch_bounds__(256) void k_base(int* __restrict__ H,
                                              const int* __restrict__ deg,
                                              const int* __restrict__ bsum,
                                              int* __restrict__ off,
                                              int* __restrict__ csr) {
    __shared__ int wtot[4];
    __shared__ int boff_s;
    int t = threadIdx.x, blk = blockIdx.x;
    int n = blk * 256 + t;
    int d = (n < NNODES) ? deg[n] : 0;
    int lane = t & 63, w = t >> 6;
    int sc = d;
#pragma unroll
    for (int o = 1; o < 64; o <<= 1) {
        int u = __shfl_up(sc, o);
        if (lane >= o) sc += u;
    }
    if (lane == 63) wtot[w] = sc;
    if (w == 0) {  // wave 0: exclusive prefix of block sums (CBLK=79 <= 128)
        int v = (lane < blk) ? bsum[lane] : 0;
        if (lane + 64 < blk) v += bsum[lane + 64];
#pragma unroll
        for (int o = 1; o < 64; o <<= 1) v += __shfl_xor(v, o);
        if (lane == 0) boff_s = v;
    }
    __syncthreads();
    int woff = 0;
    for (int i = 0; i < w; i++) woff += wtot[i];
    int excl = woff + sc - d;
    if (blk == 0 && t == 0) off[NNODES] = ETOT;
    if (n < NNODES) {
        int o0 = boff_s + excl;
        off[n] = o0;
        csr[o0] = n;          // self-loop in first slot
        int run = o0 + 1;     // reserve it
#pragma unroll 5
        for (int b = 0; b < NBLK; b++) {
            size_t idx = (size_t)b * NNODES + n;
            int tt = H[idx];
            H[idx] = run;
            run += tt;
        }
    }
}

// Scatter real edges using LDS-staged per-block bases. Zero global atomics.
__global__ __launch_bounds__(256) void k_scatter2(const int* __restrict__ ei,
                                                  const int* __restrict__ H,
                                                  int* __restrict__ csr,
                                                  const int* __restrict__ flag) {
    __shared__ int base_l[NNODES];  // 80 KB
    int t = threadIdx.x, b = blockIdx.x, f = flag[0];
    const s32x4* Hb4 = reinterpret_cast<const s32x4*>(H + (size_t)b * NNODES);
    s32x4* bl4 = reinterpret_cast<s32x4*>(base_l);
    for (int i = t; i < NNODES / 4; i += 256) bl4[i] = Hb4[i];
    __syncthreads();
    int s0 = b * EBLK;
    if (f) {
        const int* d64 = ei + 2 * NEDGES;
        for (int i0 = s0; i0 < s0 + EBLK; i0 += 512) {
            int i = i0 + 2 * t;
            s32x4 sv = *reinterpret_cast<const s32x4*>(ei + 2 * (size_t)i);
            s32x4 dv = *reinterpret_cast<const s32x4*>(d64 + 2 * (size_t)i);
            int p0 = atomicAdd(&base_l[dv[0]], 1);
            csr[p0] = sv[0];
            int p1 = atomicAdd(&base_l[dv[2]], 1);
            csr[p1] = sv[2];
        }
    } else {
        const int* d32 = ei + NEDGES;
        for (int i0 = s0; i0 < s0 + EBLK; i0 += 1024) {
            int i = i0 + 4 * t;
            s32x4 sv = *reinterpret_cast<const s32x4*>(ei + i);
            s32x4 dv = *reinterpret_cast<const s32x4*>(d32 + i);
#pragma unroll
            for (int k = 0; k < 4; k++) {
                int p = atomicAdd(&base_l[dv[k]], 1);
                csr[p] = sv[k];
            }
        }
    }
}

// ---------------- both weight transposes, one launch ----------------
__global__ void k_wt(const void* __restrict__ W1, const void* __restrict__ W2,
                     __hip_bfloat16* __restrict__ Wt1, __hip_bfloat16* __restrict__ Wt2,
                     const int* __restrict__ flag) {
    int i = blockIdx.x * 256 + threadIdx.x;  // 131072
    int which = i >> 16;
    int j = i & 65535;
    int k = j >> 8, n = j & 255;
    const void* W = which ? W2 : W1;
    __hip_bfloat16* Wt = which ? Wt2 : Wt1;
    Wt[(size_t)n * 256 + k] = __float2bfloat16(ldf(W, (size_t)k * 256 + n, flag[1]));
}

// ---------------- GEMM (16-row blocks, wave = one head's 64 cols) ----------------
// Block = 16 rows x 256 cols, 4 waves; wave w owns cols [w*64, w*64+64) == head w.
// Epilogue: H staged in LDS -> 2 coalesced 16B stores/lane (was 16 scattered 2B);
// fused es/ed scores (wave-local, head-aligned); per-head GLOBAL es max via one
// atomicMax/wave (monotone-uint encoding) feeding k_agg's bound-max softmax.
__global__ __launch_bounds__(256) void k_gemm(const void* __restrict__ A,
                                              const __hip_bfloat16* __restrict__ Bt,
                                              __hip_bfloat16* __restrict__ Hout,
                                              const void* __restrict__ a_src,
                                              const void* __restrict__ a_dst,
                                              float* __restrict__ es4, float* __restrict__ ed4,
                                              unsigned int* __restrict__ gmaxu,
                                              const int* __restrict__ flag, int force_bf) {
    __shared__ u32x4 hst4[512];  // 16 rows x 256 cols bf16 = 8 KB
    int bf   = flag[1];
    int abf  = force_bf | bf;
    int w    = threadIdx.x >> 6;
    int lane = threadIdx.x & 63;
    int mr   = lane & 15;
    int quad = lane >> 4;
    int r0   = blockIdx.x * 16;
    f32x4 acc[4];
#pragma unroll
    for (int j = 0; j < 4; j++) acc[j] = (f32x4){0.f, 0.f, 0.f, 0.f};
    size_t rowoff = (size_t)(r0 + mr) * HC;
    const __hip_bfloat16* Btw = Bt + (size_t)w * 64 * HC;
    for (int kk = 0; kk < HC; kk += 32) {
        bf16x8 a;
        if (abf) {
            a = *reinterpret_cast<const bf16x8*>((const __hip_bfloat16*)A + rowoff + kk + quad * 8);
        } else {
            const float* af = (const float*)A + rowoff + kk + quad * 8;
            f32x4 lo = *reinterpret_cast<const f32x4*>(af);
            f32x4 hi = *reinterpret_cast<const f32x4*>(af + 4);
#pragma unroll
            for (int ii = 0; ii < 4; ii++) { a[ii] = f2bs(lo[ii]); a[ii + 4] = f2bs(hi[ii]); }
        }
#pragma unroll
        for (int j = 0; j < 4; j++) {
            bf16x8 b = *reinterpret_cast<const bf16x8*>(Btw + (size_t)(j * 16 + mr) * HC + kk + quad * 8);
            acc[j] = __builtin_amdgcn_mfma_f32_16x16x32_bf16(a, b, acc[j], 0, 0, 0);
        }
    }
    // stage H tile in LDS (D frag: col=mr, row=quad*4+r)
    short* hst = reinterpret_cast<short*>(hst4);
#pragma unroll
    for (int j = 0; j < 4; j++)
#pragma unroll
        for (int r = 0; r < 4; r++)
            hst[(quad * 4 + r) * HC + w * 64 + j * 16 + mr] = f2bs(acc[j][r]);
    // fused scores for head w: es[row][w] = sum over head-w cols of h*a_src
    float ps[4] = {0.f, 0.f, 0.f, 0.f}, pd[4] = {0.f, 0.f, 0.f, 0.f};
#pragma unroll
    for (int j = 0; j < 4; j++) {
        float asv = ldf(a_src, (size_t)(w * 64 + j * 16 + mr), bf);
        float adv = ldf(a_dst, (size_t)(w * 64 + j * 16 + mr), bf);
#pragma unroll
        for (int r = 0; r < 4; r++) {
            ps[r] = fmaf(acc[j][r], asv, ps[r]);
            pd[r] = fmaf(acc[j][r], adv, pd[r]);
        }
    }
#pragma unroll
    for (int o = 1; o < 16; o <<= 1)
#pragma unroll
        for (int r = 0; r < 4; r++) {
            ps[r] += __shfl_xor(ps[r], o);
            pd[r] += __shfl_xor(pd[r], o);
        }
    // per-head global es max (upper bound for k_agg's shift)
    float pm = fmaxf(fmaxf(ps[0], ps[1]), fmaxf(ps[2], ps[3]));
    pm = fmaxf(pm, __shfl_xor(pm, 16));
    pm = fmaxf(pm, __shfl_xor(pm, 32));
    if (lane == 0) atomicMax(&gmaxu[w * 16], enc_f(pm));
    if (mr == 0)
#pragma unroll
        for (int r = 0; r < 4; r++) {
            int row = r0 + quad * 4 + r;
            es4[(size_t)row * 4 + w] = ps[r];
            ed4[(size_t)row * 4 + w] = pd[r];
        }
    __syncthreads();
    // coalesced H write: 8 KB contiguous (rows r0..r0+15)
    u32x4* dst = reinterpret_cast<u32x4*>((short*)Hout + (size_t)r0 * HC);
    dst[threadIdx.x * 2]     = hst4[threadIdx.x * 2];
    dst[threadIdx.x * 2 + 1] = hst4[threadIdx.x * 2 + 1];
}

// ---------------- fused softmax + aggregation (wave per node, persistent) ----------------
// Bound-max softmax: M[h] = leaky(global_es_max[h] + ed[n][h]) >= every edge score
// of node n (leaky monotone). pv = exp(ev - M) directly -> NO per-chunk max/sum
// butterflies, NO online rescale; dsum is lane-local, one 24-shuffle reduce per node.
// Gather: lane covers 8 cols (16B); half-waves take 8 consecutive edges; indices/
// weights via ds_read_b128 from planar LDS; packed f32x2 accumulate.
__global__ __launch_bounds__(256) void k_agg(const __hip_bfloat16* __restrict__ Hb,
                                             const float* __restrict__ es4, const float* __restrict__ ed4,
                                             const void* __restrict__ bias,
                                             const int* __restrict__ off, const int* __restrict__ csr,
                                             const unsigned int* __restrict__ gmaxu,
                                             const int* __restrict__ flag,
                                             __hip_bfloat16* __restrict__ out) {
    __shared__ float p_lds[4][4][64];  // [wave][head][edge]
    __shared__ int   s_lds[4][64];
    int wv = threadIdx.x >> 6;
    int l  = threadIdx.x & 63;
    int half = l >> 5;
    int hl   = l & 31;
    int hd8  = hl >> 3;               // head owning cols hl*8..hl*8+7
    int bf = flag[1];
    f32x4 gm;
#pragma unroll
    for (int h = 0; h < 4; h++) gm[h] = dec_f(gmaxu[h * 16]);
    int n0 = blockIdx.x * 4 + wv;
    for (int n = n0; n < NNODES; n += 10000) {
        int base = off[n], deg = off[n + 1] - base;
        f32x4 edv = *reinterpret_cast<const f32x4*>(ed4 + (size_t)n * 4);
        f32x4 M;
#pragma unroll
        for (int h = 0; h < 4; h++) {
            float t0 = gm[h] + edv[h];
            M[h] = (t0 > 0.f) ? t0 : 0.2f * t0;
        }
        f32x4 dsum = (f32x4){0.f, 0.f, 0.f, 0.f};
        f32x2 acc2[4];
#pragma unroll
        for (int d = 0; d < 4; d++) acc2[d] = (f32x2){0.f, 0.f};
        for (int c0 = 0; c0 < deg; c0 += 64) {
            int cn = min(deg - c0, 64);
            int s = 0;
            f32x4 pv = (f32x4){0.f, 0.f, 0.f, 0.f};
            if (l < cn) {
                s = csr[base + c0 + l];
                f32x4 e = *reinterpret_cast<const f32x4*>(es4 + (size_t)s * 4);
#pragma unroll
                for (int h = 0; h < 4; h++) {
                    float t = e[h] + edv[h];
                    t = (t > 0.f) ? t : 0.2f * t;
                    pv[h] = __expf(t - M[h]);
                }
            }
            s_lds[wv][l] = s;   // pad lanes -> row 0 (weight 0)
#pragma unroll
            for (int h = 0; h < 4; h++) p_lds[wv][h][l] = pv[h];
#pragma unroll
            for (int h = 0; h < 4; h++) dsum[h] += pv[h];
            // gather: half-waves take 8 consecutive edges each, 16 edges/step
            int jn = (cn + 15) & ~15;
            for (int j = 0; j < jn; j += 16) {
                int e0 = j + 8 * half;
                s32x4 sA = *reinterpret_cast<const s32x4*>(&s_lds[wv][e0]);
                s32x4 sB = *reinterpret_cast<const s32x4*>(&s_lds[wv][e0 + 4]);
                f32x4 pA = *reinterpret_cast<const f32x4*>(&p_lds[wv][hd8][e0]);
                f32x4 pB = *reinterpret_cast<const f32x4*>(&p_lds[wv][hd8][e0 + 4]);
                u32x4 hv[8];
#pragma unroll
                for (int i = 0; i < 8; i++) {
                    int sj = (i < 4) ? sA[i & 3] : sB[i & 3];
                    hv[i] = *reinterpret_cast<const u32x4*>(Hb + (size_t)sj * HC + hl * 8);
                }
#pragma unroll
                for (int i = 0; i < 8; i++) {
                    float p = (i < 4) ? pA[i & 3] : pB[i & 3];
#pragma unroll
                    for (int d = 0; d < 4; d++) {
                        unsigned int u = hv[i][d];
                        f32x2 h2;
                        h2.x = __uint_as_float(u << 16);
                        h2.y = __uint_as_float(u & 0xFFFF0000u);
                        acc2[d] += h2 * p;
                    }
                }
            }
        }
        // one denominator reduce per node
#pragma unroll
        for (int o = 32; o; o >>= 1)
#pragma unroll
            for (int h = 0; h < 4; h++) dsum[h] += __shfl_xor(dsum[h], o);
        // merge half-accumulators
#pragma unroll
        for (int d = 0; d < 4; d++) {
            acc2[d].x += __shfl_xor(acc2[d].x, 32);
            acc2[d].y += __shfl_xor(acc2[d].y, 32);
        }
        float rinv = 1.0f / fmaxf(dsum[hd8], 1e-16f);
        if (half == 0) {
            bf16x8 ov;
#pragma unroll
            for (int d = 0; d < 4; d++) {
                float v0 = acc2[d].x * rinv + ldf(bias, (size_t)hl * 8 + 2 * d, bf);
                float v1 = acc2[d].y * rinv + ldf(bias, (size_t)hl * 8 + 2 * d + 1, bf);
                ov[2 * d]     = f2bs(fmaxf(v0, 0.f));
                ov[2 * d + 1] = f2bs(fmaxf(v1, 0.f));
            }
            *reinterpret_cast<bf16x8*>(out + (size_t)n * HC + hl * 8) = ov;
        }
    }
}

// ---------------- readout: 4-row-parallel boundary-flush group sums + counts ----------------
__global__ __launch_bounds__(256) void k_groupsum(const __hip_bfloat16* __restrict__ X2,
                                                  const int* __restrict__ batch,
                                                  float* __restrict__ sx, int* __restrict__ cnt,
                                                  const int* __restrict__ flag) {
    const int RPB = NNODES / 250;  // 80
    int b = blockIdx.x, f = flag[0];
    int sub = threadIdx.x >> 6, l = threadIdx.x & 63;
    int r = b * RPB + sub;
    f32x4 acc = (f32x4){0.f, 0.f, 0.f, 0.f};
    int curg = ld_idx(batch, r, f);
    int cacc = 0;
    for (int k = 0; k < RPB / 4; k++, r += 4) {
        int g = ld_idx(batch, r, f);
        if (g != curg) {
#pragma unroll
            for (int c = 0; c < 4; c++) atomicAdd(&sx[(size_t)curg * HC + l * 4 + c], acc[c]);
            if (l == 0) atomicAdd(&cnt[curg], cacc);
            acc = (f32x4){0.f, 0.f, 0.f, 0.f}; cacc = 0; curg = g;
        }
        s16x4 hv = *reinterpret_cast<const s16x4*>(X2 + (size_t)r * HC + l * 4);
#pragma unroll
        for (int c = 0; c < 4; c++) acc[c] += bs2f(hv[c]);
        cacc++;
    }
#pragma unroll
    for (int c = 0; c < 4; c++) atomicAdd(&sx[(size_t)curg * HC + l * 4 + c], acc[c]);
    if (l == 0) atomicAdd(&cnt[curg], cacc);
}

// ---------------- final projection: one block per group, 8-way split dot + LDS reduce --------
__global__ __launch_bounds__(256) void k_final(const float* __restrict__ sx,
                                               const void* __restrict__ Wp,
                                               const void* __restrict__ bp,
                                               const int* __restrict__ cnt,
                                               const int* __restrict__ flag,
                                               void* __restrict__ out) {
    __shared__ float red[8][32];
    int g = blockIdx.x, t = threadIdx.x;
    int c = t & 31, seg = t >> 5;
    int bf = flag[1];
    const float* sxg = sx + (size_t)g * HC;
    float a = 0.f;
#pragma unroll
    for (int k = 0; k < 32; k++) {
        int kk = seg * 32 + k;
        a = fmaf(sxg[kk], ldf(Wp, (size_t)kk * DOUT + c, bf), a);
    }
    red[seg][c] = a;
    __syncthreads();
    if (t < 32) {
        float s = 0.f;
#pragma unroll
        for (int i = 0; i < 8; i++) s += red[i][t];
        int ct = cnt[g];
        float v = (ct > 0) ? (s / ct + ldf(bp, (size_t)t, bf)) : 0.f;
        if (bf) ((__hip_bfloat16*)out)[g * DOUT + t] = __float2bfloat16(v);
        else    ((float*)out)[g * DOUT + t]          = v;
    }
}

extern "C" void kernel_launch(void* const* d_in, const int* in_sizes, int n_in,
                              void* d_out, int out_size, void* d_ws, size_t ws_size,
                              hipStream_t stream) {
    (void)in_sizes; (void)n_in; (void)out_size; (void)ws_size;
    const void* x   = d_in[0];
    const int*  ei  = (const int*)d_in[1];
    const int*  bat = (const int*)d_in[2];
    const void* W1  = d_in[3];
    const void* as1 = d_in[4];
    const void* ad1 = d_in[5];
    const void* b1  = d_in[6];
    const void* W2  = d_in[7];
    const void* as2 = d_in[8];
    const void* ad2 = d_in[9];
    const void* b2  = d_in[10];
    const void* Wp  = d_in[11];
    const void* bp  = d_in[12];

    char* ws = (char*)d_ws;
    size_t o = 0;
    auto alloc = [&](size_t bytes) -> char* {
        char* p = ws + o;
        o += (bytes + 255) & ~(size_t)255;
        return p;
    };
    __hip_bfloat16* hb  = (__hip_bfloat16*)alloc((size_t)NNODES * HC * 2);  // bf16 h
    __hip_bfloat16* xb  = (__hip_bfloat16*)alloc((size_t)NNODES * HC * 2);  // bf16 layer-1 out
    __hip_bfloat16* xb2 = (__hip_bfloat16*)alloc((size_t)NNODES * HC * 2);  // bf16 layer-2 out
    __hip_bfloat16* Wt1 = (__hip_bfloat16*)alloc((size_t)HC * HC * 2);
    __hip_bfloat16* Wt2 = (__hip_bfloat16*)alloc((size_t)HC * HC * 2);
    float* es = (float*)alloc((size_t)NNODES * 4 * 4);
    float* ed = (float*)alloc((size_t)NNODES * 4 * 4);
    int* H    = (int*)alloc((size_t)NBLK * NNODES * 4);    // per-block histograms / bases
    int* deg  = (int*)alloc((size_t)NNODES * 4);
    int* off  = (int*)alloc((size_t)(NNODES + 1) * 4);
    int* csr  = (int*)alloc((size_t)ETOT * 4);
    int* bsum = (int*)alloc((size_t)CBLK * 4);
    float* sx = (float*)alloc((size_t)NGROUP * HC * 4);
    unsigned int* gmaxu = (unsigned int*)alloc(256);       // 4 heads x 64B-padded
    int* cnt  = (int*)alloc(256);
    int* flag = (int*)alloc(256);

    // probe + atomic-free CSR build (shared by both layers)
    k_probe<<<1, 256, 0, stream>>>((const unsigned int*)x, ei, flag, sx, cnt, gmaxu);
    k_lhist<<<NBLK, 256, 0, stream>>>(ei, H, flag);
    k_colsum<<<CBLK, 256, 0, stream>>>(H, deg, bsum);
    k_base<<<CBLK, 256, 0, stream>>>(H, deg, bsum, off, csr);
    k_scatter2<<<NBLK, 256, 0, stream>>>(ei, H, csr, flag);
    k_wt<<<512, 256, 0, stream>>>(W1, W2, Wt1, Wt2, flag);

    // Layer 1
    k_gemm<<<NNODES / 16, 256, 0, stream>>>(x, Wt1, hb, as1, ad1, es, ed, gmaxu, flag, 0);
    k_agg<<<2500, 256, 0, stream>>>(hb, es, ed, b1, off, csr, gmaxu, flag, xb);

    // Layer 2 (gmaxu not re-inited: lingering layer-1 max stays a valid upper bound)
    k_gemm<<<NNODES / 16, 256, 0, stream>>>(xb, Wt2, hb, as2, ad2, es, ed, gmaxu, flag, 1);
    k_agg<<<2500, 256, 0, stream>>>(hb, es, ed, b2, off, csr, gmaxu, flag, xb2);

    // Readout
    k_groupsum<<<250, 256, 0, stream>>>(xb2, bat, sx, cnt, flag);
    k_final<<<NGROUP, 256, 0, stream>>>(sx, Wp, bp, cnt, flag, d_out);
}

// Round 7
// 301.819 us; speedup vs baseline: 1.0796x; 1.0796x over previous
//
#include <hip/hip_runtime.h>
#include <hip/hip_bf16.h>
#include <cstdint>

#define NNODES 20000
#define NEDGES 640000
#define ETOT   (NEDGES + NNODES)
#define NGROUP 64
#define HC     256
#define DOUT   32
#define EBLK   5120                     // edges per CSR-build block (divides NEDGES)
#define NBLK   (NEDGES / EBLK)          // 125
#define CBLK   ((NNODES + 255) / 256)   // 79 node blocks
#define GBLK   (NNODES / 16)            // 1250 gemm blocks

typedef short bf16x8 __attribute__((ext_vector_type(8)));  // 8 bf16 in 4 VGPRs
typedef short s16x4  __attribute__((ext_vector_type(4)));
typedef float f32x4  __attribute__((ext_vector_type(4)));
typedef float f32x2  __attribute__((ext_vector_type(2)));
typedef int   s32x4  __attribute__((ext_vector_type(4)));
typedef unsigned int u32x4 __attribute__((ext_vector_type(4)));

__device__ __forceinline__ float b2f(__hip_bfloat16 v) { return __bfloat162float(v); }
__device__ __forceinline__ float bs2f(short v) {
    union { unsigned int u; float f; } c; c.u = ((unsigned int)(unsigned short)v) << 16; return c.f;
}
__device__ __forceinline__ short f2bs(float v) {
    __hip_bfloat16 b = __float2bfloat16(v);
    union { __hip_bfloat16 b; short s; } u; u.b = b; return u.s;
}
// float load robust to fp32 vs bf16 storage
__device__ __forceinline__ float ldf(const void* __restrict__ p, size_t i, int bf) {
    return bf ? __bfloat162float(((const __hip_bfloat16*)p)[i]) : ((const float*)p)[i];
}
// int load robust to int32 vs int64 storage (little-endian low word)
__device__ __forceinline__ int ld_idx(const int* __restrict__ p, size_t i, int f64) {
    return f64 ? p[2 * i] : p[i];
}

// ---------------- probe (ballot-parallel) + readout zero ----------------
// flag[0]: edge_index int64?  flag[1]: floats bf16?
__global__ void k_probe(const unsigned int* __restrict__ xw, const int* __restrict__ ei,
                        int* __restrict__ flag, float* __restrict__ sx, int* __restrict__ cnt) {
    int t = threadIdx.x;
    for (int i = t; i < NGROUP * HC; i += 256) sx[i] = 0.f;
    if (t < NGROUP) cnt[t] = 0;
    if (t < 64) {
        int l = t;
        int ones = 0, zeros = 0;
#pragma unroll
        for (int r = 0; r < 4; r++) {
            unsigned long long b1 = __ballot((xw[r * 64 + l] >> 14) & 1);
            unsigned long long b2 = __ballot(ei[2 * (r * 64 + l) + 1] == 0);
            ones  += __popcll(b1);
            zeros += __popcll(b2);
        }
        if (l == 0) { flag[1] = (ones < 64) ? 1 : 0; flag[0] = (zeros > 200) ? 1 : 0; }
    }
}

// ---------------- CSR build, atomic-free (per-block LDS histograms) ----------------
// Self-loops are NOT histogrammed: deg = colsum + 1 and csr[off[n]] = n is written
// directly by k_base. Each block handles exactly EBLK real edges -> no guards,
// 16B-aligned dwordx4 edge loads.
__global__ __launch_bounds__(256) void k_lhist(const int* __restrict__ ei,
                                               int* __restrict__ H,
                                               const int* __restrict__ flag) {
    __shared__ int hl[NNODES];  // 80 KB
    int t = threadIdx.x, b = blockIdx.x, f = flag[0];
    s32x4* hl4 = reinterpret_cast<s32x4*>(hl);
    for (int i = t; i < NNODES / 4; i += 256) hl4[i] = (s32x4){0, 0, 0, 0};
    __syncthreads();
    int s0 = b * EBLK;
    if (f) {
        const int* d64 = ei + 2 * NEDGES;   // low words at d64[2*i]
        for (int i0 = s0; i0 < s0 + EBLK; i0 += 512) {
            int i = i0 + 2 * t;
            s32x4 v = *reinterpret_cast<const s32x4*>(d64 + 2 * (size_t)i);
            atomicAdd(&hl[v[0]], 1);
            atomicAdd(&hl[v[2]], 1);
        }
    } else {
        const int* d32 = ei + NEDGES;
        for (int i0 = s0; i0 < s0 + EBLK; i0 += 1024) {
            int i = i0 + 4 * t;
            s32x4 v = *reinterpret_cast<const s32x4*>(d32 + i);
            atomicAdd(&hl[v[0]], 1); atomicAdd(&hl[v[1]], 1);
            atomicAdd(&hl[v[2]], 1); atomicAdd(&hl[v[3]], 1);
        }
    }
    __syncthreads();
    s32x4* Hb4 = reinterpret_cast<s32x4*>(H + (size_t)b * NNODES);
    for (int i = t; i < NNODES / 4; i += 256) Hb4[i] = hl4[i];
}

// deg[n] = 1 (self-loop) + sum_b H[b][n]; per-block totals for k_base's tiny scan.
__global__ __launch_bounds__(256) void k_colsum(const int* __restrict__ H,
                                                int* __restrict__ deg,
                                                int* __restrict__ bsum) {
    __shared__ int wred[4];
    int t = threadIdx.x, n = blockIdx.x * 256 + t;
    int s = 0;
    if (n < NNODES) {
#pragma unroll 5
        for (int b = 0; b < NBLK; b++) s += H[(size_t)b * NNODES + n];
        s += 1;  // self-loop
        deg[n] = s;
    }
    int r = s;
#pragma unroll
    for (int o = 1; o < 64; o <<= 1) r += __shfl_xor(r, o);
    if ((t & 63) == 0) wred[t >> 6] = r;
    __syncthreads();
    if (t == 0) bsum[blockIdx.x] = wred[0] + wred[1] + wred[2] + wred[3];
}

// Per 256-node block: block offset = scan of bsum (done in-kernel by wave 0),
// intra-block shuffle scan of deg -> off[n], self-loop csr entry at off[n], then
// per-block H bases (prefix over NBLK, +1 for the reserved self-loop slot).
__global__ __launch_bounds__(256) void k_base(int* __restrict__ H,
                                              const int* __restrict__ deg,
                                              const int* __restrict__ bsum,
                                              int* __restrict__ off,
                                              int* __restrict__ csr) {
    __shared__ int wtot[4];
    __shared__ int boff_s;
    int t = threadIdx.x, blk = blockIdx.x;
    int n = blk * 256 + t;
    int d = (n < NNODES) ? deg[n] : 0;
    int lane = t & 63, w = t >> 6;
    int sc = d;
#pragma unroll
    for (int o = 1; o < 64; o <<= 1) {
        int u = __shfl_up(sc, o);
        if (lane >= o) sc += u;
    }
    if (lane == 63) wtot[w] = sc;
    if (w == 0) {  // wave 0: exclusive prefix of block sums (CBLK=79 <= 128)
        int v = (lane < blk) ? bsum[lane] : 0;
        if (lane + 64 < blk) v += bsum[lane + 64];
#pragma unroll
        for (int o = 1; o < 64; o <<= 1) v += __shfl_xor(v, o);
        if (lane == 0) boff_s = v;
    }
    __syncthreads();
    int woff = 0;
    for (int i = 0; i < w; i++) woff += wtot[i];
    int excl = woff + sc - d;
    if (blk == 0 && t == 0) off[NNODES] = ETOT;
    if (n < NNODES) {
        int o0 = boff_s + excl;
        off[n] = o0;
        csr[o0] = n;          // self-loop in first slot
        int run = o0 + 1;     // reserve it
#pragma unroll 5
        for (int b = 0; b < NBLK; b++) {
            size_t idx = (size_t)b * NNODES + n;
            int tt = H[idx];
            H[idx] = run;
            run += tt;
        }
    }
}

// Scatter real edges using LDS-staged per-block bases. Zero global atomics.
__global__ __launch_bounds__(256) void k_scatter2(const int* __restrict__ ei,
                                                  const int* __restrict__ H,
                                                  int* __restrict__ csr,
                                                  const int* __restrict__ flag) {
    __shared__ int base_l[NNODES];  // 80 KB
    int t = threadIdx.x, b = blockIdx.x, f = flag[0];
    const s32x4* Hb4 = reinterpret_cast<const s32x4*>(H + (size_t)b * NNODES);
    s32x4* bl4 = reinterpret_cast<s32x4*>(base_l);
    for (int i = t; i < NNODES / 4; i += 256) bl4[i] = Hb4[i];
    __syncthreads();
    int s0 = b * EBLK;
    if (f) {
        const int* d64 = ei + 2 * NEDGES;
        for (int i0 = s0; i0 < s0 + EBLK; i0 += 512) {
            int i = i0 + 2 * t;
            s32x4 sv = *reinterpret_cast<const s32x4*>(ei + 2 * (size_t)i);
            s32x4 dv = *reinterpret_cast<const s32x4*>(d64 + 2 * (size_t)i);
            int p0 = atomicAdd(&base_l[dv[0]], 1);
            csr[p0] = sv[0];
            int p1 = atomicAdd(&base_l[dv[2]], 1);
            csr[p1] = sv[2];
        }
    } else {
        const int* d32 = ei + NEDGES;
        for (int i0 = s0; i0 < s0 + EBLK; i0 += 1024) {
            int i = i0 + 4 * t;
            s32x4 sv = *reinterpret_cast<const s32x4*>(ei + i);
            s32x4 dv = *reinterpret_cast<const s32x4*>(d32 + i);
#pragma unroll
            for (int k = 0; k < 4; k++) {
                int p = atomicAdd(&base_l[dv[k]], 1);
                csr[p] = sv[k];
            }
        }
    }
}

// ---------------- both weight transposes, one launch ----------------
__global__ void k_wt(const void* __restrict__ W1, const void* __restrict__ W2,
                     __hip_bfloat16* __restrict__ Wt1, __hip_bfloat16* __restrict__ Wt2,
                     const int* __restrict__ flag) {
    int i = blockIdx.x * 256 + threadIdx.x;  // 131072
    int which = i >> 16;
    int j = i & 65535;
    int k = j >> 8, n = j & 255;
    const void* W = which ? W2 : W1;
    __hip_bfloat16* Wt = which ? Wt2 : Wt1;
    Wt[(size_t)n * 256 + k] = __float2bfloat16(ldf(W, (size_t)k * 256 + n, flag[1]));
}

// ---------------- GEMM (16-row blocks, wave = one head's 64 cols) ----------------
// Block = 16 rows x 256 cols, 4 waves; wave w owns cols [w*64, w*64+64) == head w.
// Epilogue: H staged in LDS -> 2 coalesced 16B stores/lane; fused es/ed scores
// (wave-local, head-aligned). Per-head es max written CONTENTION-FREE to
// gpart[bid*4+w] (plain f32 store; the round-6 same-address atomicMax serialized
// 1250 cross-XCD atomics -> 50 us stall). k_gmax reduces gpart afterwards.
__global__ __launch_bounds__(256) void k_gemm(const void* __restrict__ A,
                                              const __hip_bfloat16* __restrict__ Bt,
                                              __hip_bfloat16* __restrict__ Hout,
                                              const void* __restrict__ a_src,
                                              const void* __restrict__ a_dst,
                                              float* __restrict__ es4, float* __restrict__ ed4,
                                              float* __restrict__ gpart,
                                              const int* __restrict__ flag, int force_bf) {
    __shared__ u32x4 hst4[512];  // 16 rows x 256 cols bf16 = 8 KB
    int bf   = flag[1];
    int abf  = force_bf | bf;
    int w    = threadIdx.x >> 6;
    int lane = threadIdx.x & 63;
    int mr   = lane & 15;
    int quad = lane >> 4;
    int r0   = blockIdx.x * 16;
    f32x4 acc[4];
#pragma unroll
    for (int j = 0; j < 4; j++) acc[j] = (f32x4){0.f, 0.f, 0.f, 0.f};
    size_t rowoff = (size_t)(r0 + mr) * HC;
    const __hip_bfloat16* Btw = Bt + (size_t)w * 64 * HC;
    for (int kk = 0; kk < HC; kk += 32) {
        bf16x8 a;
        if (abf) {
            a = *reinterpret_cast<const bf16x8*>((const __hip_bfloat16*)A + rowoff + kk + quad * 8);
        } else {
            const float* af = (const float*)A + rowoff + kk + quad * 8;
            f32x4 lo = *reinterpret_cast<const f32x4*>(af);
            f32x4 hi = *reinterpret_cast<const f32x4*>(af + 4);
#pragma unroll
            for (int ii = 0; ii < 4; ii++) { a[ii] = f2bs(lo[ii]); a[ii + 4] = f2bs(hi[ii]); }
        }
#pragma unroll
        for (int j = 0; j < 4; j++) {
            bf16x8 b = *reinterpret_cast<const bf16x8*>(Btw + (size_t)(j * 16 + mr) * HC + kk + quad * 8);
            acc[j] = __builtin_amdgcn_mfma_f32_16x16x32_bf16(a, b, acc[j], 0, 0, 0);
        }
    }
    // stage H tile in LDS (D frag: col=mr, row=quad*4+r)
    short* hst = reinterpret_cast<short*>(hst4);
#pragma unroll
    for (int j = 0; j < 4; j++)
#pragma unroll
        for (int r = 0; r < 4; r++)
            hst[(quad * 4 + r) * HC + w * 64 + j * 16 + mr] = f2bs(acc[j][r]);
    // fused scores for head w: es[row][w] = sum over head-w cols of h*a_src
    float ps[4] = {0.f, 0.f, 0.f, 0.f}, pd[4] = {0.f, 0.f, 0.f, 0.f};
#pragma unroll
    for (int j = 0; j < 4; j++) {
        float asv = ldf(a_src, (size_t)(w * 64 + j * 16 + mr), bf);
        float adv = ldf(a_dst, (size_t)(w * 64 + j * 16 + mr), bf);
#pragma unroll
        for (int r = 0; r < 4; r++) {
            ps[r] = fmaf(acc[j][r], asv, ps[r]);
            pd[r] = fmaf(acc[j][r], adv, pd[r]);
        }
    }
#pragma unroll
    for (int o = 1; o < 16; o <<= 1)
#pragma unroll
        for (int r = 0; r < 4; r++) {
            ps[r] += __shfl_xor(ps[r], o);
            pd[r] += __shfl_xor(pd[r], o);
        }
    // per-head block max (contention-free partials; reduced by k_gmax)
    float pm = fmaxf(fmaxf(ps[0], ps[1]), fmaxf(ps[2], ps[3]));
    pm = fmaxf(pm, __shfl_xor(pm, 16));
    pm = fmaxf(pm, __shfl_xor(pm, 32));
    if (lane == 0) gpart[blockIdx.x * 4 + w] = pm;
    if (mr == 0)
#pragma unroll
        for (int r = 0; r < 4; r++) {
            int row = r0 + quad * 4 + r;
            es4[(size_t)row * 4 + w] = ps[r];
            ed4[(size_t)row * 4 + w] = pd[r];
        }
    __syncthreads();
    // coalesced H write: consecutive 16B per lane (conflict-free ds_read_b128)
    u32x4* dst = reinterpret_cast<u32x4*>((short*)Hout + (size_t)r0 * HC);
    dst[threadIdx.x]       = hst4[threadIdx.x];
    dst[threadIdx.x + 256] = hst4[threadIdx.x + 256];
}

// 1 tiny block: gmax4[h] = max over 1250 blocks of gpart[b*4+h].
__global__ void k_gmax(const float* __restrict__ gpart, float* __restrict__ gmax4) {
    int l = threadIdx.x & 63, wv = threadIdx.x >> 6;  // wave = head
    float m = -INFINITY;
    for (int i = l; i < GBLK; i += 64) m = fmaxf(m, gpart[i * 4 + wv]);
#pragma unroll
    for (int o = 32; o; o >>= 1) m = fmaxf(m, __shfl_xor(m, o));
    if (l == 0) gmax4[wv] = m;
}

// ---------------- fused softmax + aggregation (wave per node, persistent) ----------------
// Bound-max softmax: M[h] = leaky(global_es_max[h] + ed[n][h]) >= every edge score
// of node n (leaky monotone). pv = exp(ev - M) directly -> NO per-chunk max/sum
// butterflies, NO online rescale; dsum is lane-local, one reduce per node.
// Gather: lane covers 8 cols (16B); half-waves take 8 consecutive edges; indices/
// weights via ds_read_b128 from planar LDS; packed f32x2 accumulate.
__global__ __launch_bounds__(256) void k_agg(const __hip_bfloat16* __restrict__ Hb,
                                             const float* __restrict__ es4, const float* __restrict__ ed4,
                                             const void* __restrict__ bias,
                                             const int* __restrict__ off, const int* __restrict__ csr,
                                             const float* __restrict__ gmax4,
                                             const int* __restrict__ flag,
                                             __hip_bfloat16* __restrict__ out) {
    __shared__ float p_lds[4][4][64];  // [wave][head][edge]
    __shared__ int   s_lds[4][64];
    int wv = threadIdx.x >> 6;
    int l  = threadIdx.x & 63;
    int half = l >> 5;
    int hl   = l & 31;
    int hd8  = hl >> 3;               // head owning cols hl*8..hl*8+7
    int bf = flag[1];
    f32x4 gm = *reinterpret_cast<const f32x4*>(gmax4);
    int n0 = blockIdx.x * 4 + wv;
    for (int n = n0; n < NNODES; n += 10000) {
        int base = off[n], deg = off[n + 1] - base;
        f32x4 edv = *reinterpret_cast<const f32x4*>(ed4 + (size_t)n * 4);
        f32x4 M;
#pragma unroll
        for (int h = 0; h < 4; h++) {
            float t0 = gm[h] + edv[h];
            M[h] = (t0 > 0.f) ? t0 : 0.2f * t0;
        }
        f32x4 dsum = (f32x4){0.f, 0.f, 0.f, 0.f};
        f32x2 acc2[4];
#pragma unroll
        for (int d = 0; d < 4; d++) acc2[d] = (f32x2){0.f, 0.f};
        for (int c0 = 0; c0 < deg; c0 += 64) {
            int cn = min(deg - c0, 64);
            int s = 0;
            f32x4 pv = (f32x4){0.f, 0.f, 0.f, 0.f};
            if (l < cn) {
                s = csr[base + c0 + l];
                f32x4 e = *reinterpret_cast<const f32x4*>(es4 + (size_t)s * 4);
#pragma unroll
                for (int h = 0; h < 4; h++) {
                    float t = e[h] + edv[h];
                    t = (t > 0.f) ? t : 0.2f * t;
                    pv[h] = __expf(t - M[h]);
                }
            }
            s_lds[wv][l] = s;   // pad lanes -> row 0 (weight 0)
#pragma unroll
            for (int h = 0; h < 4; h++) p_lds[wv][h][l] = pv[h];
#pragma unroll
            for (int h = 0; h < 4; h++) dsum[h] += pv[h];
            // gather: half-waves take 8 consecutive edges each, 16 edges/step
            int jn = (cn + 15) & ~15;
            for (int j = 0; j < jn; j += 16) {
                int e0 = j + 8 * half;
                s32x4 sA = *reinterpret_cast<const s32x4*>(&s_lds[wv][e0]);
                s32x4 sB = *reinterpret_cast<const s32x4*>(&s_lds[wv][e0 + 4]);
                f32x4 pA = *reinterpret_cast<const f32x4*>(&p_lds[wv][hd8][e0]);
                f32x4 pB = *reinterpret_cast<const f32x4*>(&p_lds[wv][hd8][e0 + 4]);
                u32x4 hv[8];
#pragma unroll
                for (int i = 0; i < 8; i++) {
                    int sj = (i < 4) ? sA[i & 3] : sB[i & 3];
                    hv[i] = *reinterpret_cast<const u32x4*>(Hb + (size_t)sj * HC + hl * 8);
                }
#pragma unroll
                for (int i = 0; i < 8; i++) {
                    float p = (i < 4) ? pA[i & 3] : pB[i & 3];
#pragma unroll
                    for (int d = 0; d < 4; d++) {
                        unsigned int u = hv[i][d];
                        f32x2 h2;
                        h2.x = __uint_as_float(u << 16);
                        h2.y = __uint_as_float(u & 0xFFFF0000u);
                        acc2[d] += h2 * p;
                    }
                }
            }
        }
        // one denominator reduce per node
#pragma unroll
        for (int o = 32; o; o >>= 1)
#pragma unroll
            for (int h = 0; h < 4; h++) dsum[h] += __shfl_xor(dsum[h], o);
        // merge half-accumulators
#pragma unroll
        for (int d = 0; d < 4; d++) {
            acc2[d].x += __shfl_xor(acc2[d].x, 32);
            acc2[d].y += __shfl_xor(acc2[d].y, 32);
        }
        float rinv = 1.0f / fmaxf(dsum[hd8], 1e-16f);
        if (half == 0) {
            bf16x8 ov;
#pragma unroll
            for (int d = 0; d < 4; d++) {
                float v0 = acc2[d].x * rinv + ldf(bias, (size_t)hl * 8 + 2 * d, bf);
                float v1 = acc2[d].y * rinv + ldf(bias, (size_t)hl * 8 + 2 * d + 1, bf);
                ov[2 * d]     = f2bs(fmaxf(v0, 0.f));
                ov[2 * d + 1] = f2bs(fmaxf(v1, 0.f));
            }
            *reinterpret_cast<bf16x8*>(out + (size_t)n * HC + hl * 8) = ov;
        }
    }
}

// ---------------- readout: 4-row-parallel boundary-flush group sums + counts ----------------
__global__ __launch_bounds__(256) void k_groupsum(const __hip_bfloat16* __restrict__ X2,
                                                  const int* __restrict__ batch,
                                                  float* __restrict__ sx, int* __restrict__ cnt,
                                                  const int* __restrict__ flag) {
    const int RPB = NNODES / 250;  // 80
    int b = blockIdx.x, f = flag[0];
    int sub = threadIdx.x >> 6, l = threadIdx.x & 63;
    int r = b * RPB + sub;
    f32x4 acc = (f32x4){0.f, 0.f, 0.f, 0.f};
    int curg = ld_idx(batch, r, f);
    int cacc = 0;
    for (int k = 0; k < RPB / 4; k++, r += 4) {
        int g = ld_idx(batch, r, f);
        if (g != curg) {
#pragma unroll
            for (int c = 0; c < 4; c++) atomicAdd(&sx[(size_t)curg * HC + l * 4 + c], acc[c]);
            if (l == 0) atomicAdd(&cnt[curg], cacc);
            acc = (f32x4){0.f, 0.f, 0.f, 0.f}; cacc = 0; curg = g;
        }
        s16x4 hv = *reinterpret_cast<const s16x4*>(X2 + (size_t)r * HC + l * 4);
#pragma unroll
        for (int c = 0; c < 4; c++) acc[c] += bs2f(hv[c]);
        cacc++;
    }
#pragma unroll
    for (int c = 0; c < 4; c++) atomicAdd(&sx[(size_t)curg * HC + l * 4 + c], acc[c]);
    if (l == 0) atomicAdd(&cnt[curg], cacc);
}

// ---------------- final projection: one block per group, 8-way split dot + LDS reduce --------
__global__ __launch_bounds__(256) void k_final(const float* __restrict__ sx,
                                               const void* __restrict__ Wp,
                                               const void* __restrict__ bp,
                                               const int* __restrict__ cnt,
                                               const int* __restrict__ flag,
                                               void* __restrict__ out) {
    __shared__ float red[8][32];
    int g = blockIdx.x, t = threadIdx.x;
    int c = t & 31, seg = t >> 5;
    int bf = flag[1];
    const float* sxg = sx + (size_t)g * HC;
    float a = 0.f;
#pragma unroll
    for (int k = 0; k < 32; k++) {
        int kk = seg * 32 + k;
        a = fmaf(sxg[kk], ldf(Wp, (size_t)kk * DOUT + c, bf), a);
    }
    red[seg][c] = a;
    __syncthreads();
    if (t < 32) {
        float s = 0.f;
#pragma unroll
        for (int i = 0; i < 8; i++) s += red[i][t];
        int ct = cnt[g];
        float v = (ct > 0) ? (s / ct + ldf(bp, (size_t)t, bf)) : 0.f;
        if (bf) ((__hip_bfloat16*)out)[g * DOUT + t] = __float2bfloat16(v);
        else    ((float*)out)[g * DOUT + t]          = v;
    }
}

extern "C" void kernel_launch(void* const* d_in, const int* in_sizes, int n_in,
                              void* d_out, int out_size, void* d_ws, size_t ws_size,
                              hipStream_t stream) {
    (void)in_sizes; (void)n_in; (void)out_size; (void)ws_size;
    const void* x   = d_in[0];
    const int*  ei  = (const int*)d_in[1];
    const int*  bat = (const int*)d_in[2];
    const void* W1  = d_in[3];
    const void* as1 = d_in[4];
    const void* ad1 = d_in[5];
    const void* b1  = d_in[6];
    const void* W2  = d_in[7];
    const void* as2 = d_in[8];
    const void* ad2 = d_in[9];
    const void* b2  = d_in[10];
    const void* Wp  = d_in[11];
    const void* bp  = d_in[12];

    char* ws = (char*)d_ws;
    size_t o = 0;
    auto alloc = [&](size_t bytes) -> char* {
        char* p = ws + o;
        o += (bytes + 255) & ~(size_t)255;
        return p;
    };
    __hip_bfloat16* hb  = (__hip_bfloat16*)alloc((size_t)NNODES * HC * 2);  // bf16 h
    __hip_bfloat16* xb  = (__hip_bfloat16*)alloc((size_t)NNODES * HC * 2);  // bf16 layer-1 out
    __hip_bfloat16* xb2 = (__hip_bfloat16*)alloc((size_t)NNODES * HC * 2);  // bf16 layer-2 out
    __hip_bfloat16* Wt1 = (__hip_bfloat16*)alloc((size_t)HC * HC * 2);
    __hip_bfloat16* Wt2 = (__hip_bfloat16*)alloc((size_t)HC * HC * 2);
    float* es = (float*)alloc((size_t)NNODES * 4 * 4);
    float* ed = (float*)alloc((size_t)NNODES * 4 * 4);
    int* H    = (int*)alloc((size_t)NBLK * NNODES * 4);    // per-block histograms / bases
    int* deg  = (int*)alloc((size_t)NNODES * 4);
    int* off  = (int*)alloc((size_t)(NNODES + 1) * 4);
    int* csr  = (int*)alloc((size_t)ETOT * 4);
    int* bsum = (int*)alloc((size_t)CBLK * 4);
    float* gpart = (float*)alloc((size_t)GBLK * 4 * 4);    // per-gemm-block head maxes
    float* gmax4 = (float*)alloc(256);                     // reduced per-head max
    float* sx = (float*)alloc((size_t)NGROUP * HC * 4);
    int* cnt  = (int*)alloc(256);
    int* flag = (int*)alloc(256);

    // probe + atomic-free CSR build (shared by both layers)
    k_probe<<<1, 256, 0, stream>>>((const unsigned int*)x, ei, flag, sx, cnt);
    k_lhist<<<NBLK, 256, 0, stream>>>(ei, H, flag);
    k_colsum<<<CBLK, 256, 0, stream>>>(H, deg, bsum);
    k_base<<<CBLK, 256, 0, stream>>>(H, deg, bsum, off, csr);
    k_scatter2<<<NBLK, 256, 0, stream>>>(ei, H, csr, flag);
    k_wt<<<512, 256, 0, stream>>>(W1, W2, Wt1, Wt2, flag);

    // Layer 1
    k_gemm<<<GBLK, 256, 0, stream>>>(x, Wt1, hb, as1, ad1, es, ed, gpart, flag, 0);
    k_gmax<<<1, 256, 0, stream>>>(gpart, gmax4);
    k_agg<<<2500, 256, 0, stream>>>(hb, es, ed, b1, off, csr, gmax4, flag, xb);

    // Layer 2
    k_gemm<<<GBLK, 256, 0, stream>>>(xb, Wt2, hb, as2, ad2, es, ed, gpart, flag, 1);
    k_gmax<<<1, 256, 0, stream>>>(gpart, gmax4);
    k_agg<<<2500, 256, 0, stream>>>(hb, es, ed, b2, off, csr, gmax4, flag, xb2);

    // Readout
    k_groupsum<<<250, 256, 0, stream>>>(xb2, bat, sx, cnt, flag);
    k_final<<<NGROUP, 256, 0, stream>>>(sx, Wp, bp, cnt, flag, d_out);
}